// Round 1
// baseline (304.488 us; speedup 1.0000x reference)
//
#include <hip/hip_runtime.h>

#define TWO_PI_F 6.283185307179586f

// Problem constants (from setup_inputs)
#define C_O   512
#define C_CIN 512
#define C_K   16
#define C_KS  7
#define C_NI  16
#define C_NO  16

#define OUT0_SIZE (C_O * C_NI * C_CIN * C_NO)   // 67,108,864
#define OUT1_SIZE (C_O * C_NO * C_KS * C_KS)    // 401,408

#define WV_STRIDE 19   // 16 data + 1 dup + 2 pad; odd -> conflict-free strided LDS reads

// ---------------------------------------------------------------------------
// Kernel 1: circular-lerp broadcast.
// out0[o,ni,c,no] = (1-f)*W[o,c,i0] + f*W[o,c,i1],  (i0,i1,f) from (ni,no).
// One thread per (o,c) pair; 256 pairs per block.
// ---------------------------------------------------------------------------
__global__ __launch_bounds__(256) void interp_H_kernel(
    const float* __restrict__ in_H,
    const float* __restrict__ out_H,
    const float* __restrict__ weight_H,
    float* __restrict__ out0)
{
    __shared__ float s_wv[256 * WV_STRIDE];
    __shared__ float s_t[C_NI * C_NO];

    const int tid = threadIdx.x;
    const int p   = blockIdx.x * 256 + tid;   // pair index = o*512 + c
    const int o   = p >> 9;
    const int c   = p & 511;

    // Per-(ni,no) interpolation coordinate t in [0,16): i0=floor(t)&15, f=fract(t)
    {
        const int ni = tid >> 4;
        const int no = tid & 15;
        float x = in_H[ni] - out_H[no];
        float r = fmodf(x, TWO_PI_F);
        if (r < 0.0f) r += TWO_PI_F;
        s_t[tid] = r * (16.0f / TWO_PI_F);
    }

    // Load this pair's 16-float row of weight_H into LDS (+ duplicate slot 16)
    const float4* wsrc = reinterpret_cast<const float4*>(weight_H) + (size_t)p * 4;
    float4 w0 = wsrc[0];
    float4 w1 = wsrc[1];
    float4 w2 = wsrc[2];
    float4 w3 = wsrc[3];
    float* wv = &s_wv[tid * WV_STRIDE];
    wv[0]  = w0.x; wv[1]  = w0.y; wv[2]  = w0.z; wv[3]  = w0.w;
    wv[4]  = w1.x; wv[5]  = w1.y; wv[6]  = w1.z; wv[7]  = w1.w;
    wv[8]  = w2.x; wv[9]  = w2.y; wv[10] = w2.z; wv[11] = w2.w;
    wv[12] = w3.x; wv[13] = w3.y; wv[14] = w3.z; wv[15] = w3.w;
    wv[16] = w0.x;                      // wrap-around duplicate: i1 = i0+1 always

    __syncthreads();

    // Output base for this (o,c): flat = ((o*16 + ni)*512 + c)*16 + no
    size_t obase = (size_t)o * (C_NI * C_CIN * C_NO) + (size_t)c * C_NO;

    for (int ni = 0; ni < C_NI; ++ni) {
        float res[16];
#pragma unroll
        for (int no = 0; no < 16; ++no) {
            float tt = s_t[ni * 16 + no];       // wave-uniform LDS read (broadcast)
            float fl = floorf(tt);
            int   i0 = ((int)fl) & 15;
            float f  = tt - fl;
            float a  = wv[i0];                  // ds_read2_b32 pair
            float b  = wv[i0 + 1];
            res[no] = (1.0f - f) * a + f * b;
        }
        float4* dst = reinterpret_cast<float4*>(out0 + obase + (size_t)ni * (C_CIN * C_NO));
        dst[0] = make_float4(res[0],  res[1],  res[2],  res[3]);
        dst[1] = make_float4(res[4],  res[5],  res[6],  res[7]);
        dst[2] = make_float4(res[8],  res[9],  res[10], res[11]);
        dst[3] = make_float4(res[12], res[13], res[14], res[15]);
    }
}

// ---------------------------------------------------------------------------
// Kernel 2: rotated-grid bilinear sampling of 7x7 kernels (zero padding).
// out1[o,no,0,ky,kx] = mask[ky,kx] * bilinear(weight[o,0], R(-out_H[no]) @ grid)
// ---------------------------------------------------------------------------
__global__ __launch_bounds__(256) void bilin_kernel(
    const float* __restrict__ out_H,
    const float* __restrict__ weight,
    const float* __restrict__ grid_Rn,
    const float* __restrict__ mask,
    float* __restrict__ out1)
{
    int idx = blockIdx.x * 256 + threadIdx.x;
    if (idx >= OUT1_SIZE) return;

    int pix = idx % 49;            // ky*7 + kx
    int no  = (idx / 49) & 15;
    int o   = idx / (49 * 16);

    float gx = grid_Rn[pix * 2 + 0];
    float gy = grid_Rn[pix * 2 + 1];

    float ang = -out_H[no];
    float sn, cs;
    sincosf(ang, &sn, &cs);

    float x = cs * gx - sn * gy;
    float y = sn * gx + cs * gy;

    // align_corners mapping to [0, 6]
    float X = (x + 1.0f) * 3.0f;
    float Y = (y + 1.0f) * 3.0f;

    float x0f = floorf(X), y0f = floorf(Y);
    float wx = X - x0f,    wy = Y - y0f;
    int   x0 = (int)x0f,   y0 = (int)y0f;

    const float* img = weight + o * 49;

    auto gat = [&](int yy, int xx) -> float {
        bool v = (yy >= 0) & (yy < 7) & (xx >= 0) & (xx < 7);
        int yc = min(max(yy, 0), 6);
        int xc = min(max(xx, 0), 6);
        float val = img[yc * 7 + xc];
        return v ? val : 0.0f;
    };

    float r = (1.0f - wy) * (1.0f - wx) * gat(y0,     x0)
            + (1.0f - wy) * wx          * gat(y0,     x0 + 1)
            + wy          * (1.0f - wx) * gat(y0 + 1, x0)
            + wy          * wx          * gat(y0 + 1, x0 + 1);

    out1[idx] = mask[pix] * r;
}

extern "C" void kernel_launch(void* const* d_in, const int* in_sizes, int n_in,
                              void* d_out, int out_size, void* d_ws, size_t ws_size,
                              hipStream_t stream) {
    const float* in_H     = (const float*)d_in[0];
    const float* out_H    = (const float*)d_in[1];
    const float* weight_H = (const float*)d_in[2];
    const float* weight   = (const float*)d_in[3];
    // d_in[4] = grid_H (implicit in uniform-grid formula), unused
    const float* grid_Rn  = (const float*)d_in[5];
    const float* mask     = (const float*)d_in[6];

    float* out0 = (float*)d_out;
    float* out1 = out0 + OUT0_SIZE;

    // Kernel 1: 512*512 (o,c) pairs, 256 per block
    hipLaunchKernelGGL(interp_H_kernel, dim3((C_O * C_CIN) / 256), dim3(256), 0, stream,
                       in_H, out_H, weight_H, out0);

    // Kernel 2: one thread per output element
    hipLaunchKernelGGL(bilin_kernel, dim3((OUT1_SIZE + 255) / 256), dim3(256), 0, stream,
                       out_H, weight, grid_Rn, mask, out1);
}

// Round 2
// 69.416 us; speedup vs baseline: 4.3864x; 4.3864x over previous
//
#include <hip/hip_runtime.h>

#define TWO_PI_F 6.283185307179586f

// Problem constants (from setup_inputs)
#define C_O   512
#define C_CIN 512
#define C_K   16
#define C_KS  7
#define C_NI  16
#define C_NO  16

#define OUT0_SIZE (C_O * C_NI * C_CIN * C_NO)   // 67,108,864
#define OUT1_SIZE (C_O * C_NO * C_KS * C_KS)    // 401,408

// LDS row stride for weight rows: 16 data + 1 wrap-dup + 1 pad = 18 floats (72 B).
// 18c mod 32 hits 16 distinct banks over 16 consecutive c -> conflict-spread.
// 72 B is 8B-aligned -> stage via float2 LDS writes.
#define SW_STRIDE 18

// ---------------------------------------------------------------------------
// Kernel 1: circular-lerp broadcast, one block per (o, ni).
// out0[o,ni,c,no] = (1-f)*W[o,c,i0] + f*W[o,c,i0+1], (i0,f) from (ni,no).
// Block writes a contiguous 32 KB region; every wave store is a contiguous 1 KB.
// ---------------------------------------------------------------------------
__global__ __launch_bounds__(256) void interp_H_kernel(
    const float* __restrict__ in_H,
    const float* __restrict__ out_H,
    const float* __restrict__ weight_H,
    float* __restrict__ out0)
{
    __shared__ float s_w[C_CIN * SW_STRIDE];   // 36,864 B
    __shared__ float s_t[C_NO];

    const int tid = threadIdx.x;
    const int blk = blockIdx.x;          // blk = o*16 + ni
    const int o   = blk >> 4;
    const int ni  = blk & 15;

    // t coordinate per no (16 values, block-uniform)
    if (tid < 16) {
        float x = in_H[ni] - out_H[tid];
        float r = fmodf(x, TWO_PI_F);
        if (r < 0.0f) r += TWO_PI_F;
        s_t[tid] = r * (16.0f / TWO_PI_F);
    }

    // Stage weight_H[o, :, :] (512 x 16 floats = 32 KB) into LDS, stride 18 + dup
    const float4* wsrc = reinterpret_cast<const float4*>(weight_H) + (size_t)o * 2048;
#pragma unroll
    for (int j = 0; j < 8; ++j) {
        int f = j * 256 + tid;           // float4 index: c = f/4, part = f%4
        float4 v = wsrc[f];
        int c    = f >> 2;
        int part = f & 3;
        float* row = &s_w[c * SW_STRIDE + part * 4];
        reinterpret_cast<float2*>(row)[0] = make_float2(v.x, v.y);
        reinterpret_cast<float2*>(row)[1] = make_float2(v.z, v.w);
        if (part == 0) s_w[c * SW_STRIDE + 16] = v.x;   // wrap duplicate
    }
    __syncthreads();

    // This thread covers no = 4*(tid&3) + e, e=0..3 (same for all 8 stores)
    const int q = tid & 3;
    int   i0e[4];
    float fe[4];
#pragma unroll
    for (int e = 0; e < 4; ++e) {
        float tt = s_t[q * 4 + e];
        float fl = floorf(tt);
        i0e[e] = ((int)fl) & 15;
        fe[e]  = tt - fl;
    }

    const int crow = tid >> 2;           // c sub-offset: store j covers c = j*64 + crow
    float4* obase = reinterpret_cast<float4*>(out0) + ((size_t)blk << 11);

#pragma unroll
    for (int j = 0; j < 8; ++j) {
        const float* wv = &s_w[(j * 64 + crow) * SW_STRIDE];
        float4 res;
        {
            float a = wv[i0e[0]], b = wv[i0e[0] + 1];
            res.x = (1.0f - fe[0]) * a + fe[0] * b;
        }
        {
            float a = wv[i0e[1]], b = wv[i0e[1] + 1];
            res.y = (1.0f - fe[1]) * a + fe[1] * b;
        }
        {
            float a = wv[i0e[2]], b = wv[i0e[2] + 1];
            res.z = (1.0f - fe[2]) * a + fe[2] * b;
        }
        {
            float a = wv[i0e[3]], b = wv[i0e[3] + 1];
            res.w = (1.0f - fe[3]) * a + fe[3] * b;
        }
        obase[j * 256 + tid] = res;      // contiguous 1 KB per wave store
    }
}

// ---------------------------------------------------------------------------
// Kernel 2: rotated-grid bilinear sampling of 7x7 kernels (zero padding).
// ---------------------------------------------------------------------------
__global__ __launch_bounds__(256) void bilin_kernel(
    const float* __restrict__ out_H,
    const float* __restrict__ weight,
    const float* __restrict__ grid_Rn,
    const float* __restrict__ mask,
    float* __restrict__ out1)
{
    int idx = blockIdx.x * 256 + threadIdx.x;
    if (idx >= OUT1_SIZE) return;

    int pix = idx % 49;            // ky*7 + kx
    int no  = (idx / 49) & 15;
    int o   = idx / (49 * 16);

    float gx = grid_Rn[pix * 2 + 0];
    float gy = grid_Rn[pix * 2 + 1];

    float ang = -out_H[no];
    float sn, cs;
    sincosf(ang, &sn, &cs);

    float x = cs * gx - sn * gy;
    float y = sn * gx + cs * gy;

    float X = (x + 1.0f) * 3.0f;
    float Y = (y + 1.0f) * 3.0f;

    float x0f = floorf(X), y0f = floorf(Y);
    float wx = X - x0f,    wy = Y - y0f;
    int   x0 = (int)x0f,   y0 = (int)y0f;

    const float* img = weight + o * 49;

    auto gat = [&](int yy, int xx) -> float {
        bool v = (yy >= 0) & (yy < 7) & (xx >= 0) & (xx < 7);
        int yc = min(max(yy, 0), 6);
        int xc = min(max(xx, 0), 6);
        float val = img[yc * 7 + xc];
        return v ? val : 0.0f;
    };

    float r = (1.0f - wy) * (1.0f - wx) * gat(y0,     x0)
            + (1.0f - wy) * wx          * gat(y0,     x0 + 1)
            + wy          * (1.0f - wx) * gat(y0 + 1, x0)
            + wy          * wx          * gat(y0 + 1, x0 + 1);

    out1[idx] = mask[pix] * r;
}

extern "C" void kernel_launch(void* const* d_in, const int* in_sizes, int n_in,
                              void* d_out, int out_size, void* d_ws, size_t ws_size,
                              hipStream_t stream) {
    const float* in_H     = (const float*)d_in[0];
    const float* out_H    = (const float*)d_in[1];
    const float* weight_H = (const float*)d_in[2];
    const float* weight   = (const float*)d_in[3];
    // d_in[4] = grid_H (implicit in uniform-grid formula), unused
    const float* grid_Rn  = (const float*)d_in[5];
    const float* mask     = (const float*)d_in[6];

    float* out0 = (float*)d_out;
    float* out1 = out0 + OUT0_SIZE;

    // Kernel 1: one block per (o, ni)
    hipLaunchKernelGGL(interp_H_kernel, dim3(C_O * C_NI), dim3(256), 0, stream,
                       in_H, out_H, weight_H, out0);

    // Kernel 2: one thread per output element
    hipLaunchKernelGGL(bilin_kernel, dim3((OUT1_SIZE + 255) / 256), dim3(256), 0, stream,
                       out_H, weight, grid_Rn, mask, out1);
}

// Round 3
// 55.161 us; speedup vs baseline: 5.5200x; 1.2584x over previous
//
#include <hip/hip_runtime.h>

#define TWO_PI_F 6.283185307179586f

// Problem constants (from setup_inputs)
#define C_O   512
#define C_CIN 512
#define C_K   16
#define C_KS  7
#define C_NI  16
#define C_NO  16

#define OUT0_SIZE (C_O * C_NI * C_CIN * C_NO)   // 67,108,864
#define OUT1_SIZE (C_O * C_NO * C_KS * C_KS)    // 401,408

// LDS row stride: 16 data + 1 wrap-dup + 1 pad = 18 floats. 18c mod 32 spreads
// 16 consecutive rows over 16 distinct banks; 8B-aligned for float2 staging.
#define SW_STRIDE 18

#define BILIN_BLOCKS  392    // OUT1_SIZE / 1024 exactly
#define INTERP_BLOCKS 2048   // C_O * 4  (4 ni per block)

typedef float f32x4 __attribute__((ext_vector_type(4)));

// ---------------------------------------------------------------------------
// Fused kernel. Blocks [0, 392): bilinear sampling (out1).
// Blocks [392, 392+2048): circular-lerp broadcast (out0), one block per
// (o, ni-group-of-4). 1024 threads; 2 blocks/CU -> 32 waves/CU.
// ---------------------------------------------------------------------------
__global__ __launch_bounds__(1024) void fused_kernel(
    const float* __restrict__ in_H,
    const float* __restrict__ out_H,
    const float* __restrict__ weight_H,
    const float* __restrict__ weight,
    const float* __restrict__ grid_Rn,
    const float* __restrict__ mask,
    float* __restrict__ out0,
    float* __restrict__ out1)
{
    __shared__ float s_w[C_CIN * SW_STRIDE];   // 36,864 B
    __shared__ float s_t[64];

    const int tid = threadIdx.x;
    const int bid = blockIdx.x;

    if (bid < BILIN_BLOCKS) {
        // ---- bilinear branch: out1[o,no,0,ky,kx] ----
        int idx = bid * 1024 + tid;            // < OUT1_SIZE exactly
        int pix = idx % 49;                    // ky*7 + kx
        int no  = (idx / 49) & 15;
        int o   = idx / (49 * 16);

        float gx = grid_Rn[pix * 2 + 0];
        float gy = grid_Rn[pix * 2 + 1];

        float ang = -out_H[no];
        float sn, cs;
        sincosf(ang, &sn, &cs);

        float x = cs * gx - sn * gy;
        float y = sn * gx + cs * gy;

        float X = (x + 1.0f) * 3.0f;           // align_corners map to [0,6]
        float Y = (y + 1.0f) * 3.0f;

        float x0f = floorf(X), y0f = floorf(Y);
        float wx = X - x0f,    wy = Y - y0f;
        int   x0 = (int)x0f,   y0 = (int)y0f;

        const float* img = weight + o * 49;

        auto gat = [&](int yy, int xx) -> float {
            bool v = (yy >= 0) & (yy < 7) & (xx >= 0) & (xx < 7);
            int yc = min(max(yy, 0), 6);
            int xc = min(max(xx, 0), 6);
            float val = img[yc * 7 + xc];
            return v ? val : 0.0f;
        };

        float r = (1.0f - wy) * (1.0f - wx) * gat(y0,     x0)
                + (1.0f - wy) * wx          * gat(y0,     x0 + 1)
                + wy          * (1.0f - wx) * gat(y0 + 1, x0)
                + wy          * wx          * gat(y0 + 1, x0 + 1);

        out1[idx] = mask[pix] * r;
        return;
    }

    // ---- interp branch ----
    const int ibid = bid - BILIN_BLOCKS;
    const int o    = ibid >> 2;
    const int nig  = ibid & 3;                 // ni group: ni = nig*4 + ni_l

    // t coordinate for this block's 4 ni x 16 no
    if (tid < 64) {
        int ni_l = tid >> 4;
        int no   = tid & 15;
        float x = in_H[nig * 4 + ni_l] - out_H[no];
        float r = fmodf(x, TWO_PI_F);
        if (r < 0.0f) r += TWO_PI_F;
        s_t[tid] = r * (16.0f / TWO_PI_F);
    }

    // Stage weight_H[o,:,:] (512 rows x 16 floats = 32 KB), stride 18 + wrap dup
    const float4* wsrc = reinterpret_cast<const float4*>(weight_H) + (size_t)o * 2048;
#pragma unroll
    for (int j = 0; j < 2; ++j) {
        int f = j * 1024 + tid;                // float4 index
        float4 v = wsrc[f];
        int c    = f >> 2;
        int part = f & 3;
        float* row = &s_w[c * SW_STRIDE + part * 4];
        reinterpret_cast<float2*>(row)[0] = make_float2(v.x, v.y);
        reinterpret_cast<float2*>(row)[1] = make_float2(v.z, v.w);
        if (part == 0) s_w[c * SW_STRIDE + 16] = v.x;
    }
    __syncthreads();

    const int q    = tid & 3;                  // no quad: no = q*4 + e
    const int crow = tid >> 2;
    f32x4* obase = reinterpret_cast<f32x4*>(out0)
                 + ((size_t)o << 15) + ((size_t)nig << 13);

#pragma unroll
    for (int it = 0; it < 8; ++it) {
        int ni_l = it >> 1;                    // uniform across wave
        int c    = ((it & 1) << 8) + crow;
        const float* wv = &s_w[c * SW_STRIDE];
        float r0, r1, r2, r3;
        {
            float tt = s_t[ni_l * 16 + q * 4 + 0];
            float fl = floorf(tt); int i0 = ((int)fl) & 15; float fr = tt - fl;
            r0 = (1.0f - fr) * wv[i0] + fr * wv[i0 + 1];
        }
        {
            float tt = s_t[ni_l * 16 + q * 4 + 1];
            float fl = floorf(tt); int i0 = ((int)fl) & 15; float fr = tt - fl;
            r1 = (1.0f - fr) * wv[i0] + fr * wv[i0 + 1];
        }
        {
            float tt = s_t[ni_l * 16 + q * 4 + 2];
            float fl = floorf(tt); int i0 = ((int)fl) & 15; float fr = tt - fl;
            r2 = (1.0f - fr) * wv[i0] + fr * wv[i0 + 1];
        }
        {
            float tt = s_t[ni_l * 16 + q * 4 + 3];
            float fl = floorf(tt); int i0 = ((int)fl) & 15; float fr = tt - fl;
            r3 = (1.0f - fr) * wv[i0] + fr * wv[i0 + 1];
        }
        f32x4 res = {r0, r1, r2, r3};
        __builtin_nontemporal_store(res, obase + it * 1024 + tid);  // 1 KB/wave store
    }
}

extern "C" void kernel_launch(void* const* d_in, const int* in_sizes, int n_in,
                              void* d_out, int out_size, void* d_ws, size_t ws_size,
                              hipStream_t stream) {
    const float* in_H     = (const float*)d_in[0];
    const float* out_H    = (const float*)d_in[1];
    const float* weight_H = (const float*)d_in[2];
    const float* weight   = (const float*)d_in[3];
    // d_in[4] = grid_H (implicit in uniform-grid formula), unused
    const float* grid_Rn  = (const float*)d_in[5];
    const float* mask     = (const float*)d_in[6];

    float* out0 = (float*)d_out;
    float* out1 = out0 + OUT0_SIZE;

    hipLaunchKernelGGL(fused_kernel, dim3(BILIN_BLOCKS + INTERP_BLOCKS), dim3(1024),
                       0, stream,
                       in_H, out_H, weight_H, weight, grid_Rn, mask, out0, out1);
}